// Round 10
// baseline (204.355 us; speedup 1.0000x reference)
//
#include <hip/hip_runtime.h>
#include <hip/hip_bf16.h>

// EdgeBlock: out[e] = relu(concat(edge[e], node[recv[e]], node[send[e]], g) @ W1 + b1) @ W2 + b2
// Round 10: FACTORED node GEMM. P[n] = node[n] @ [W1r | W1s] precomputed (bf16, sigma-layout,
// 51.2MB ws). Per edge: h = e@W1e (K=64 MFMA) + P_r[recv] + P_s[send] + g1 -> relu -> GEMM2.
//  - MFMA per tile halves; edge A-frags loaded direct from global (sequential rows, L1)
//  - P gathered 256B/side from L3 table, summed in regs, bounced through padded P_lds
//  - r8's proven 2-barrier chassis, h sigma/SWZ layout, W2F unchanged
// Fallback (ws too small for P): r8's full node-table kernel (proven 124 us).

typedef __bf16 bf16x8 __attribute__((ext_vector_type(8)));
typedef __bf16 bf16x2 __attribute__((ext_vector_type(2)));
typedef float f32x4 __attribute__((ext_vector_type(4)));

#define GRID_MAIN 2048
#define SWZ(x) ((x) ^ (((x) >> 3) & 7))
// ws layout:
//   [0, 49152)       W1F bf16 frag-order (full K=192; P-path uses f<2, prep_P uses f 2..5)
//   [49152, 65536)   W2F bf16 frag-order, sigma baked in
//   [65536, 66048)   g1 f32 [128] = b1 + global_attr @ W1[192:256]
//   [66560, ...)     P-path: P_ws bf16 [N][256] (sigma-physical per side)  |  node-path: node_bf16
#define WS_AUX_OFF 66560

__global__ void prep_kernel(const float* __restrict__ W1, const float* __restrict__ b1,
                            const float* __restrict__ W2, const float* __restrict__ gattr,
                            __bf16* __restrict__ W1F, __bf16* __restrict__ W2F,
                            float* __restrict__ g1) {
    int tid = blockIdx.x * blockDim.x + threadIdx.x;
    if (tid < 128 * 192) {
        int n = tid / 192, k = tid % 192;
        int w = n >> 5, nt2 = (n >> 4) & 1, c = n & 15;
        int f = k >> 5, g = (k >> 3) & 3, j = k & 7;
        W1F[((((w * 2 + nt2) * 6 + f) * 64) + c + 16 * g) * 8 + j] = (__bf16)W1[k * 128 + n];
    } else if (tid < 128 * 192 + 64 * 128) {
        int t = tid - 128 * 192;
        int n = t / 128, p = t % 128;   // p = PHYSICAL k slot (h/P column)
        int w = n >> 4, c = n & 15;
        int ks = p >> 5, g = (p >> 3) & 3, j = p & 7;
        // sigma: physical p = w1*32 + 2*cc + half  <->  klog = w1*32 + half*16 + cc
        int klog = (p >> 5) * 32 + (p & 1) * 16 + ((p >> 1) & 15);
        W2F[(((w * 4 + ks) * 64) + c + 16 * g) * 8 + j] = (__bf16)W2[klog * 64 + n];
    } else if (tid < 128 * 192 + 64 * 128 + 128) {
        int n = tid - (128 * 192 + 64 * 128);
        float acc = b1[n];
        for (int j = 0; j < 64; ++j) acc += gattr[j] * W1[(192 + j) * 128 + n];
        g1[n] = acc;
    }
}

__global__ __launch_bounds__(256) void node_conv_kernel(const float* __restrict__ nf,
                                                        __bf16* __restrict__ nb, int n8) {
    int t = blockIdx.x * blockDim.x + threadIdx.x;
    if (t < n8) {
        f32x4 a = *(const f32x4*)(nf + (long)t * 8);
        f32x4 b = *(const f32x4*)(nf + (long)t * 8 + 4);
        bf16x8 o;
#pragma unroll
        for (int j = 0; j < 4; ++j) { o[j] = (__bf16)a[j]; o[4 + j] = (__bf16)b[j]; }
        *(bf16x8*)(nb + (long)t * 8) = o;
    }
}

__device__ __forceinline__ f32x4 mk4(float v) {
    f32x4 r; r[0] = v; r[1] = v; r[2] = v; r[3] = v; return r;
}

__device__ __forceinline__ bf16x8 cvt8(f32x4 lo, f32x4 hi) {
    bf16x8 t;
#pragma unroll
    for (int j = 0; j < 4; ++j) { t[j] = (__bf16)lo[j]; t[4 + j] = (__bf16)hi[j]; }
    return t;
}

// ---- prep_P: P[n][256] = node[n] @ [W1r | W1s], stored bf16 in sigma-physical slots ----
__global__ __launch_bounds__(256) void prep_p_kernel(
    const float* __restrict__ node_feats, const __bf16* __restrict__ W1F,
    __bf16* __restrict__ P_ws, int N)
{
    __shared__ __bf16 A_lds[4 * 2 * 64 * 8];   // [mt][f][lane]x16B : 8KB
    __shared__ __bf16 o_tile[64][264];         // 33KB transpose tile (row 528B, 16B-aligned)

    const int lane = threadIdx.x & 63;
    const int v    = threadIdx.x >> 6;   // wave 0..3 owns global P cols [v*64, v*64+64)
    const int c    = lane & 15;
    const int g    = lane >> 4;

    // pinned B-frags: col C = v*64 + nt*16 + c; side = v>>1; L = (v&1)*64 + nt*16 + c
    bf16x8 wp[4][2];
#pragma unroll
    for (int nt = 0; nt < 4; ++nt)
#pragma unroll
        for (int f = 0; f < 2; ++f) {
            int w1  = (v & 1) * 2 + (nt >> 1);
            int nt2 = nt & 1;
            int fw  = 2 + (v >> 1) * 2 + f;   // W1 k-rows 64..191
            wp[nt][f] = *(const bf16x8*)(W1F + (((w1 * 2 + nt2) * 6 + fw) * 64 + lane) * 8);
        }

    const int n0 = blockIdx.x * 64;
    {
        int row = n0 + v * 16 + c; if (row > N - 1) row = N - 1;
        const float* p = node_feats + (long)row * 64 + g * 8;
        f32x4 s0 = *(const f32x4*)(p);
        f32x4 s1 = *(const f32x4*)(p + 4);
        f32x4 s2 = *(const f32x4*)(p + 32);
        f32x4 s3 = *(const f32x4*)(p + 36);
        __bf16* ab = A_lds + (v * 2) * 512 + lane * 8;
        *(bf16x8*)(ab)       = cvt8(s0, s1);   // f=0: k 0..31
        *(bf16x8*)(ab + 512) = cvt8(s2, s3);   // f=1: k 32..63
    }
    __syncthreads();

    f32x4 acc[4][4];
#pragma unroll
    for (int mt = 0; mt < 4; ++mt)
#pragma unroll
        for (int nt = 0; nt < 4; ++nt) acc[mt][nt] = mk4(0.f);
#pragma unroll
    for (int mt = 0; mt < 4; ++mt)
#pragma unroll
        for (int f = 0; f < 2; ++f) {
            bf16x8 a = *(const bf16x8*)(A_lds + ((mt * 2 + f) * 64 + lane) * 8);
#pragma unroll
            for (int nt = 0; nt < 4; ++nt)
                acc[mt][nt] = __builtin_amdgcn_mfma_f32_16x16x32_bf16(a, wp[nt][f], acc[mt][nt], 0, 0, 0);
        }

    // transpose to row-major with sigma-physical slot
#pragma unroll
    for (int mt = 0; mt < 4; ++mt)
#pragma unroll
        for (int nt = 0; nt < 4; ++nt)
#pragma unroll
            for (int r = 0; r < 4; ++r) {
                int row  = mt * 16 + g * 4 + r;
                int slot = (v >> 1) * 128 + ((v & 1) * 2 + (nt >> 1)) * 32 + 2 * c + (nt & 1);
                o_tile[row][slot] = (__bf16)acc[mt][nt][r];
            }
    __syncthreads();

    // coalesced store: thread handles (row = tid>>2, quarter q = tid&3)
    {
        int row = threadIdx.x >> 2, q = threadIdx.x & 3;
        long nrow = (long)n0 + row;
        if (nrow < N) {
#pragma unroll
            for (int k = 0; k < 8; ++k) {
                bf16x8 vld = *(const bf16x8*)&o_tile[row][q * 64 + k * 8];
                *(bf16x8*)(P_ws + nrow * 256 + q * 64 + k * 8) = vld;
            }
        }
    }
}

// ---- main (P-path) ----
__global__ __launch_bounds__(256) void edge_mlp_p(
    const float* __restrict__ edge_feats, const __bf16* __restrict__ P_ws,
    const int* __restrict__ senders, const int* __restrict__ receivers,
    const __bf16* __restrict__ W1F, const __bf16* __restrict__ W2F,
    const float* __restrict__ g1, const float* __restrict__ b2,
    float* __restrict__ out, int E, int numTiles)
{
    __shared__ __bf16 P_l[64 * 136];           // summed P rows, stride 272B (17408 B)
    __shared__ __bf16 h_frag[4 * 4 * 64 * 8];  // 16 KB (r8 layout)
    char* pb = (char*)P_l;

    const int lane = threadIdx.x & 63;
    const int w    = threadIdx.x >> 6;
    const int c    = lane & 15;
    const int g    = lane >> 4;
    const int G    = gridDim.x;

    // pinned weights: W1 edge block (f<2) + W2
    bf16x8 wb1[2][2];
#pragma unroll
    for (int nt2 = 0; nt2 < 2; ++nt2)
#pragma unroll
        for (int f = 0; f < 2; ++f)
            wb1[nt2][f] = *(const bf16x8*)(W1F + (((w * 2 + nt2) * 6 + f) * 64 + lane) * 8);
    bf16x8 wb2[4];
#pragma unroll
    for (int ks = 0; ks < 4; ++ks)
        wb2[ks] = *(const bf16x8*)(W2F + ((w * 4 + ks) * 64 + lane) * 8);
    const float g1v0 = g1[w * 32 + c];
    const float g1v1 = g1[w * 32 + 16 + c];
    const float b2v  = b2[w * 16 + c];
    const int sr = SWZ(c * 4 + g);
    const int eg = (lane >> 4);     // edge-group offset for P stage
    const int ch = (lane & 15);     // 16B chunk index

    for (int t = blockIdx.x; t < numTiles; t += G) {
        // ---- stage P: gather both sides, sum, write P_lds ----
        bf16x8 pr0, pr1, pr2, pr3, ps0, ps1, ps2, ps3;
        {
            long e0 = (long)t * 64 + w * 16 + eg;
#pragma unroll
            for (int j = 0; j < 4; ++j) {
                long e = e0 + 4 * j; if (e > (long)E - 1) e = (long)E - 1;
                int ir = receivers[e];
                int is = senders[e];
                bf16x8 a = *(const bf16x8*)(P_ws + (long)ir * 256 + ch * 8);
                bf16x8 b = *(const bf16x8*)(P_ws + (long)is * 256 + 128 + ch * 8);
                if (j == 0) { pr0 = a; ps0 = b; }
                else if (j == 1) { pr1 = a; ps1 = b; }
                else if (j == 2) { pr2 = a; ps2 = b; }
                else { pr3 = a; ps3 = b; }
            }
        }
#pragma unroll
        for (int j = 0; j < 4; ++j) {
            bf16x8 a = (j == 0) ? pr0 : (j == 1) ? pr1 : (j == 2) ? pr2 : pr3;
            bf16x8 b = (j == 0) ? ps0 : (j == 1) ? ps1 : (j == 2) ? ps2 : ps3;
            bf16x8 sm;
#pragma unroll
            for (int k = 0; k < 8; ++k) sm[k] = (__bf16)((float)a[k] + (float)b[k]);
            *(bf16x8*)(pb + (w * 16 + 4 * j + eg) * 272 + ch * 16) = sm;
        }

        // B1: P_lds visible
        asm volatile("s_waitcnt lgkmcnt(0)" ::: "memory");
        __builtin_amdgcn_s_barrier();

        // ---- GEMM1 (K=64): A-frags direct from global (sequential rows, L1) ----
        f32x4 acc0[4], acc1[4];
#pragma unroll
        for (int mt = 0; mt < 4; ++mt) { acc0[mt] = mk4(g1v0); acc1[mt] = mk4(g1v1); }
#pragma unroll
        for (int mt = 0; mt < 4; ++mt) {
            long row = (long)t * 64 + mt * 16 + c; if (row > (long)E - 1) row = (long)E - 1;
            const float* pe = edge_feats + row * 64 + g * 8;
#pragma unroll
            for (int f = 0; f < 2; ++f) {
                bf16x8 a = cvt8(*(const f32x4*)(pe + f * 32), *(const f32x4*)(pe + f * 32 + 4));
                acc0[mt] = __builtin_amdgcn_mfma_f32_16x16x32_bf16(a, wb1[0][f], acc0[mt], 0, 0, 0);
                acc1[mt] = __builtin_amdgcn_mfma_f32_16x16x32_bf16(a, wb1[1][f], acc1[mt], 0, 0, 0);
            }
        }

        // ---- h = relu(E + P) -> swizzled frag-order h (r8 layout) ----
#pragma unroll
        for (int mt = 0; mt < 4; ++mt)
#pragma unroll
            for (int r = 0; r < 4; ++r) {
                int e = mt * 16 + g * 4 + r;
                unsigned pu = *(const unsigned*)(pb + e * 272 + w * 64 + (c << 2));
                float plo = __uint_as_float(pu << 16);
                float phi = __uint_as_float(pu & 0xffff0000u);
                float v0 = acc0[mt][r] + plo; v0 = v0 > 0.f ? v0 : 0.f;
                float v1 = acc1[mt][r] + phi; v1 = v1 > 0.f ? v1 : 0.f;
                bf16x2 pk; pk[0] = (__bf16)v0; pk[1] = (__bf16)v1;
                int s = SWZ(g * 16 + r * 4 + (c >> 2));
                *(bf16x2*)&h_frag[(mt * 4 + w) * 512 + s * 8 + ((c & 3) << 1)] = pk;
            }

        // B2: h visible (also orders P_lds WAR for next stage)
        asm volatile("s_waitcnt lgkmcnt(0)" ::: "memory");
        __builtin_amdgcn_s_barrier();

        // ---- GEMM2 ----
        f32x4 acc2[4];
#pragma unroll
        for (int mt = 0; mt < 4; ++mt) acc2[mt] = mk4(b2v);
#pragma unroll
        for (int mt = 0; mt < 4; ++mt)
#pragma unroll
            for (int ks = 0; ks < 4; ++ks) {
                bf16x8 ah = *(const bf16x8*)&h_frag[(mt * 4 + ks) * 512 + sr * 8];
                acc2[mt] = __builtin_amdgcn_mfma_f32_16x16x32_bf16(ah, wb2[ks], acc2[mt], 0, 0, 0);
            }

        // ---- stores ----
#pragma unroll
        for (int mt = 0; mt < 4; ++mt)
#pragma unroll
            for (int r = 0; r < 4; ++r) {
                long orow = (long)t * 64 + mt * 16 + g * 4 + r;
                if (orow < E) out[orow * 64 + w * 16 + c] = acc2[mt][r];
            }
        // no end barrier: next B1 orders h-WAR; B2 ordered P-WAR
    }
}

// ---- r8's proven node-table kernel (fallback path, 124 us) ----
__global__ __launch_bounds__(256) void edge_mlp_kernel(
    const float* __restrict__ edge_feats, const __bf16* __restrict__ node_bf,
    const int* __restrict__ senders, const int* __restrict__ receivers,
    const __bf16* __restrict__ W1F, const __bf16* __restrict__ W2F,
    const float* __restrict__ g1, const float* __restrict__ b2,
    float* __restrict__ out, int E, int numTiles)
{
    __shared__ __bf16 smem[20480];   // A 12KB + h 8... A [4][6][64]x16B @0..12288, h @12288

    const int lane = threadIdx.x & 63;
    const int w    = threadIdx.x >> 6;
    const int c    = lane & 15;
    const int g    = lane >> 4;
    const int G    = gridDim.x;

    bf16x8 wb1[2][6];
#pragma unroll
    for (int nt2 = 0; nt2 < 2; ++nt2)
#pragma unroll
        for (int f = 0; f < 6; ++f)
            wb1[nt2][f] = *(const bf16x8*)(W1F + (((w * 2 + nt2) * 6 + f) * 64 + lane) * 8);
    bf16x8 wb2[4];
#pragma unroll
    for (int ks = 0; ks < 4; ++ks)
        wb2[ks] = *(const bf16x8*)(W2F + ((w * 4 + ks) * 64 + lane) * 8);
    const float g1v0 = g1[w * 32 + c];
    const float g1v1 = g1[w * 32 + 16 + c];
    const float b2v  = b2[w * 16 + c];
    const int sr = SWZ(c * 4 + g);

    for (int t = blockIdx.x; t < numTiles; t += G) {
        long rc = (long)t * 64 + w * 16 + c;
        if (rc > (long)E - 1) rc = (long)E - 1;
        int iR = receivers[rc], iS = senders[rc];
        const __bf16* pr = node_bf + ((long)iR << 6) + g * 8;
        const __bf16* ps = node_bf + ((long)iS << 6) + g * 8;
        bf16x8 snr0 = *(const bf16x8*)(pr);
        bf16x8 snr1 = *(const bf16x8*)(pr + 32);
        bf16x8 sns0 = *(const bf16x8*)(ps);
        bf16x8 sns1 = *(const bf16x8*)(ps + 32);
        const float* pe = edge_feats + (rc << 6) + g * 8;
        f32x4 se0 = *(const f32x4*)(pe);      f32x4 se1 = *(const f32x4*)(pe + 4);
        f32x4 se2 = *(const f32x4*)(pe + 32); f32x4 se3 = *(const f32x4*)(pe + 36);

        __bf16* ab = smem + w * 3072 + lane * 8;
        *(bf16x8*)(ab)        = cvt8(se0, se1);
        *(bf16x8*)(ab + 512)  = cvt8(se2, se3);
        *(bf16x8*)(ab + 1024) = snr0;
        *(bf16x8*)(ab + 1536) = snr1;
        *(bf16x8*)(ab + 2048) = sns0;
        *(bf16x8*)(ab + 2560) = sns1;
        asm volatile("s_waitcnt lgkmcnt(0)" ::: "memory");
        __builtin_amdgcn_s_barrier();

        f32x4 acc0[4], acc1[4];
#pragma unroll
        for (int mt = 0; mt < 4; ++mt) { acc0[mt] = mk4(g1v0); acc1[mt] = mk4(g1v1); }
#pragma unroll
        for (int mt = 0; mt < 4; ++mt)
#pragma unroll
            for (int f = 0; f < 6; ++f) {
                bf16x8 a = *(const bf16x8*)(smem + ((mt * 6 + f) * 64 + lane) * 8);
                acc0[mt] = __builtin_amdgcn_mfma_f32_16x16x32_bf16(a, wb1[0][f], acc0[mt], 0, 0, 0);
                acc1[mt] = __builtin_amdgcn_mfma_f32_16x16x32_bf16(a, wb1[1][f], acc1[mt], 0, 0, 0);
            }
#pragma unroll
        for (int mt = 0; mt < 4; ++mt)
#pragma unroll
            for (int r = 0; r < 4; ++r) {
                float v0 = acc0[mt][r]; v0 = v0 > 0.f ? v0 : 0.f;
                float v1 = acc1[mt][r]; v1 = v1 > 0.f ? v1 : 0.f;
                bf16x2 pk; pk[0] = (__bf16)v0; pk[1] = (__bf16)v1;
                int s = SWZ(g * 16 + r * 4 + (c >> 2));
                *(bf16x2*)&smem[12288 + (mt * 4 + w) * 512 + s * 8 + ((c & 3) << 1)] = pk;
            }
        asm volatile("s_waitcnt lgkmcnt(0)" ::: "memory");
        __builtin_amdgcn_s_barrier();

        f32x4 acc2[4];
#pragma unroll
        for (int mt = 0; mt < 4; ++mt) acc2[mt] = mk4(b2v);
#pragma unroll
        for (int mt = 0; mt < 4; ++mt)
#pragma unroll
            for (int ks = 0; ks < 4; ++ks) {
                bf16x8 ah = *(const bf16x8*)&smem[12288 + (mt * 4 + ks) * 512 + sr * 8];
                acc2[mt] = __builtin_amdgcn_mfma_f32_16x16x32_bf16(ah, wb2[ks], acc2[mt], 0, 0, 0);
            }
#pragma unroll
        for (int mt = 0; mt < 4; ++mt)
#pragma unroll
            for (int r = 0; r < 4; ++r) {
                long orow = (long)t * 64 + mt * 16 + g * 4 + r;
                if (orow < E) out[orow * 64 + w * 16 + c] = acc2[mt][r];
            }
        asm volatile("s_waitcnt lgkmcnt(0)" ::: "memory");
        __builtin_amdgcn_s_barrier();
    }
}

extern "C" void kernel_launch(void* const* d_in, const int* in_sizes, int n_in,
                              void* d_out, int out_size, void* d_ws, size_t ws_size,
                              hipStream_t stream) {
    const float* edge_feats = (const float*)d_in[0];
    const float* node_feats = (const float*)d_in[1];
    const float* gattr      = (const float*)d_in[2];
    const int*   senders    = (const int*)d_in[3];
    const int*   receivers  = (const int*)d_in[4];
    const float* W1         = (const float*)d_in[5];
    const float* b1         = (const float*)d_in[6];
    const float* W2         = (const float*)d_in[7];
    const float* b2         = (const float*)d_in[8];
    float* out = (float*)d_out;

    const int E = in_sizes[3];        // N_EDGES
    const int N = in_sizes[1] / 64;   // N_NODES

    char* ws = (char*)d_ws;
    __bf16* W1F = (__bf16*)ws;
    __bf16* W2F = (__bf16*)(ws + 49152);
    float*  g1  = (float*)(ws + 49152 + 16384);
    __bf16* aux = (__bf16*)(ws + WS_AUX_OFF);

    int prep_total = 128 * 192 + 64 * 128 + 128;
    prep_kernel<<<(prep_total + 255) / 256, 256, 0, stream>>>(W1, b1, W2, gattr, W1F, W2F, g1);

    const int numTiles = (E + 63) / 64;
    int grid = numTiles < GRID_MAIN ? numTiles : GRID_MAIN;

    const size_t ws_need_P = (size_t)WS_AUX_OFF + (size_t)N * 256 * 2;
    if (ws_size >= ws_need_P) {
        // factored path: prep_P then P-main
        prep_p_kernel<<<(N + 63) / 64, 256, 0, stream>>>(node_feats, W1F, aux, N);
        edge_mlp_p<<<grid, 256, 0, stream>>>(edge_feats, aux, senders, receivers,
                                             W1F, W2F, g1, b2, out, E, numTiles);
    } else {
        // r8 proven path: bf16 node table
        int n8 = N * 8;
        node_conv_kernel<<<(n8 + 255) / 256, 256, 0, stream>>>(node_feats, aux, n8);
        edge_mlp_kernel<<<grid, 256, 0, stream>>>(edge_feats, aux, senders, receivers,
                                                  W1F, W2F, g1, b2, out, E, numTiles);
    }
}

// Round 11
// 121.469 us; speedup vs baseline: 1.6824x; 1.6824x over previous
//
#include <hip/hip_runtime.h>
#include <hip/hip_bf16.h>

// EdgeBlock: out[e] = relu(concat(edge[e], node[recv[e]], node[send[e]], g) @ W1 + b1) @ W2 + b2
// Round 11 = r8 chassis (best, 124us) + two minimal deltas:
//  - T5 s_setprio(1) around both MFMA clusters (4 independent blocks/CU at uncorrelated
//    phases = the regime where setprio pays; m191)
//  - grid 1024: exactly 4 blocks/CU, one generation, 2x tiles/block (amortize prologue)
// Everything else identical to r8: frag-order pinned weights, sigma+SWZ h layout,
// 2 lgkm-only barriers/tile, T14 1-deep gather prefetch, 2-deep idx prefetch.

typedef __bf16 bf16x8 __attribute__((ext_vector_type(8)));
typedef __bf16 bf16x2 __attribute__((ext_vector_type(2)));
typedef float f32x4 __attribute__((ext_vector_type(4)));

#define GRID_MAIN 1024
#define SWZ(x) ((x) ^ (((x) >> 3) & 7))
// ws layout:
//   [0, 49152)       W1F bf16 frag-order
//   [49152, 65536)   W2F bf16 frag-order, sigma (h physical-k permutation) baked in
//   [65536, 66048)   g1 f32 [128] = b1 + global_attr @ W1[192:256]
//   [66560, ...)     node_bf16 [N][64]
#define WS_NODEBF_OFF 66560

__global__ void prep_kernel(const float* __restrict__ W1, const float* __restrict__ b1,
                            const float* __restrict__ W2, const float* __restrict__ gattr,
                            __bf16* __restrict__ W1F, __bf16* __restrict__ W2F,
                            float* __restrict__ g1) {
    int tid = blockIdx.x * blockDim.x + threadIdx.x;
    if (tid < 128 * 192) {
        int n = tid / 192, k = tid % 192;
        int w = n >> 5, nt2 = (n >> 4) & 1, c = n & 15;
        int f = k >> 5, g = (k >> 3) & 3, j = k & 7;
        W1F[((((w * 2 + nt2) * 6 + f) * 64) + c + 16 * g) * 8 + j] = (__bf16)W1[k * 128 + n];
    } else if (tid < 128 * 192 + 64 * 128) {
        int t = tid - 128 * 192;
        int n = t / 128, p = t % 128;   // p = PHYSICAL k slot (h_frag column)
        int w = n >> 4, c = n & 15;
        int ks = p >> 5, g = (p >> 3) & 3, j = p & 7;
        // sigma: physical p = w1*32 + 2*cc + half  <->  klog = w1*32 + half*16 + cc
        int klog = (p >> 5) * 32 + (p & 1) * 16 + ((p >> 1) & 15);
        W2F[(((w * 4 + ks) * 64) + c + 16 * g) * 8 + j] = (__bf16)W2[klog * 64 + n];
    } else if (tid < 128 * 192 + 64 * 128 + 128) {
        int n = tid - (128 * 192 + 64 * 128);
        float acc = b1[n];
        for (int j = 0; j < 64; ++j) acc += gattr[j] * W1[(192 + j) * 128 + n];
        g1[n] = acc;
    }
}

__global__ __launch_bounds__(256) void node_conv_kernel(const float* __restrict__ nf,
                                                        __bf16* __restrict__ nb, int n8) {
    int t = blockIdx.x * blockDim.x + threadIdx.x;
    if (t < n8) {
        f32x4 a = *(const f32x4*)(nf + (long)t * 8);
        f32x4 b = *(const f32x4*)(nf + (long)t * 8 + 4);
        bf16x8 o;
#pragma unroll
        for (int j = 0; j < 4; ++j) { o[j] = (__bf16)a[j]; o[4 + j] = (__bf16)b[j]; }
        *(bf16x8*)(nb + (long)t * 8) = o;
    }
}

__device__ __forceinline__ f32x4 mk4(float v) {
    f32x4 r; r[0] = v; r[1] = v; r[2] = v; r[3] = v; return r;
}

__device__ __forceinline__ bf16x8 cvt8(f32x4 lo, f32x4 hi) {
    bf16x8 t;
#pragma unroll
    for (int j = 0; j < 4; ++j) { t[j] = (__bf16)lo[j]; t[4 + j] = (__bf16)hi[j]; }
    return t;
}

__global__ __launch_bounds__(256) void edge_mlp_kernel(
    const float* __restrict__ edge_feats, const __bf16* __restrict__ node_bf,
    const int* __restrict__ senders, const int* __restrict__ receivers,
    const __bf16* __restrict__ W1F, const __bf16* __restrict__ W2F,
    const float* __restrict__ g1, const float* __restrict__ b2,
    float* __restrict__ out, int E, int numTiles)
{
    // A tile [mt=4][f=6][lane=64]x16B at [0,12288); h tile (swizzled) at [12288,20480)
    __shared__ __bf16 smem[20480];   // 40960 B

    const int lane = threadIdx.x & 63;
    const int w    = threadIdx.x >> 6;
    const int c    = lane & 15;
    const int g    = lane >> 4;
    const int G    = gridDim.x;

    // ---- pinned weights: 16 coalesced dwordx4 loads, once per block ----
    bf16x8 wb1[2][6];
#pragma unroll
    for (int nt2 = 0; nt2 < 2; ++nt2)
#pragma unroll
        for (int f = 0; f < 6; ++f)
            wb1[nt2][f] = *(const bf16x8*)(W1F + (((w * 2 + nt2) * 6 + f) * 64 + lane) * 8);
    bf16x8 wb2[4];
#pragma unroll
    for (int ks = 0; ks < 4; ++ks)
        wb2[ks] = *(const bf16x8*)(W2F + ((w * 4 + ks) * 64 + lane) * 8);
    const float g1v0 = g1[w * 32 + c];
    const float g1v1 = g1[w * 32 + 16 + c];
    const float b2v  = b2[w * 16 + c];

    // hoisted swizzled READ slot for GEMM2
    const int sr = SWZ(c * 4 + g);

    // ---- prologue ----
    bf16x8 snr0, snr1, sns0, sns1;
    f32x4 se0, se1, se2, se3;
    int iRa, iSa, iRb, iSb;
    {
        long r0 = (long)blockIdx.x * 64 + w * 16 + c;
        if (r0 > (long)E - 1) r0 = (long)E - 1;
        int iR0 = receivers[r0], iS0 = senders[r0];
        const __bf16* pr = node_bf + ((long)iR0 << 6) + g * 8;
        const __bf16* ps = node_bf + ((long)iS0 << 6) + g * 8;
        snr0 = *(const bf16x8*)(pr);
        snr1 = *(const bf16x8*)(pr + 32);
        sns0 = *(const bf16x8*)(ps);
        sns1 = *(const bf16x8*)(ps + 32);
        const float* pe = edge_feats + (r0 << 6) + g * 8;
        se0 = *(const f32x4*)(pe);      se1 = *(const f32x4*)(pe + 4);
        se2 = *(const f32x4*)(pe + 32); se3 = *(const f32x4*)(pe + 36);
        long r1 = ((long)blockIdx.x + G) * 64 + w * 16 + c;
        if (r1 > (long)E - 1) r1 = (long)E - 1;
        iRa = receivers[r1]; iSa = senders[r1];
        long r2 = ((long)blockIdx.x + 2L * G) * 64 + w * 16 + c;
        if (r2 > (long)E - 1) r2 = (long)E - 1;
        iRb = receivers[r2]; iSb = senders[r2];
    }

    for (int t = blockIdx.x; t < numTiles; t += G) {
        // ---- stage current tile -> A ----
        __bf16* ab = smem + w * 3072 + lane * 8;
        *(bf16x8*)(ab)        = cvt8(se0, se1);
        *(bf16x8*)(ab + 512)  = cvt8(se2, se3);
        *(bf16x8*)(ab + 1024) = snr0;
        *(bf16x8*)(ab + 1536) = snr1;
        *(bf16x8*)(ab + 2048) = sns0;
        *(bf16x8*)(ab + 2560) = sns1;

        // ---- T14: issue NEXT tile's gathers; rotate 2-deep idx ----
        {
            const __bf16* pr = node_bf + ((long)iRa << 6) + g * 8;
            const __bf16* ps = node_bf + ((long)iSa << 6) + g * 8;
            snr0 = *(const bf16x8*)(pr);
            snr1 = *(const bf16x8*)(pr + 32);
            sns0 = *(const bf16x8*)(ps);
            sns1 = *(const bf16x8*)(ps + 32);
            long rce = ((long)t + G) * 64 + w * 16 + c;
            if (rce > (long)E - 1) rce = (long)E - 1;
            const float* pe = edge_feats + (rce << 6) + g * 8;
            se0 = *(const f32x4*)(pe);      se1 = *(const f32x4*)(pe + 4);
            se2 = *(const f32x4*)(pe + 32); se3 = *(const f32x4*)(pe + 36);
            iRa = iRb; iSa = iSb;
            long r3 = ((long)t + 3L * G) * 64 + w * 16 + c;
            if (r3 > (long)E - 1) r3 = (long)E - 1;
            iRb = receivers[r3]; iSb = senders[r3];
        }
        __builtin_amdgcn_sched_barrier(0);

        // B1: A visible; VMEM prefetch stays in flight (lgkm-only)
        asm volatile("s_waitcnt lgkmcnt(0)" ::: "memory");
        __builtin_amdgcn_s_barrier();

        // ---- GEMM1 (setprio-wrapped) ----
        f32x4 acc0[4], acc1[4];
#pragma unroll
        for (int mt = 0; mt < 4; ++mt) { acc0[mt] = mk4(g1v0); acc1[mt] = mk4(g1v1); }
        __builtin_amdgcn_s_setprio(1);
#pragma unroll
        for (int mt = 0; mt < 4; ++mt)
#pragma unroll
            for (int f = 0; f < 6; ++f) {
                bf16x8 a = *(const bf16x8*)(smem + ((mt * 6 + f) * 64 + lane) * 8);
                acc0[mt] = __builtin_amdgcn_mfma_f32_16x16x32_bf16(a, wb1[0][f], acc0[mt], 0, 0, 0);
                acc1[mt] = __builtin_amdgcn_mfma_f32_16x16x32_bf16(a, wb1[1][f], acc1[mt], 0, 0, 0);
            }
        __builtin_amdgcn_s_setprio(0);

        // ---- relu -> swizzled frag-order h ----
#pragma unroll
        for (int mt = 0; mt < 4; ++mt)
#pragma unroll
            for (int r = 0; r < 4; ++r) {
                float v0 = acc0[mt][r]; v0 = v0 > 0.f ? v0 : 0.f;
                float v1 = acc1[mt][r]; v1 = v1 > 0.f ? v1 : 0.f;
                bf16x2 pk; pk[0] = (__bf16)v0; pk[1] = (__bf16)v1;
                int s = SWZ(g * 16 + r * 4 + (c >> 2));
                *(bf16x2*)&smem[12288 + (mt * 4 + w) * 512 + s * 8 + ((c & 3) << 1)] = pk;
            }

        // B2: h visible (also orders A-WAR for next iteration's stage)
        asm volatile("s_waitcnt lgkmcnt(0)" ::: "memory");
        __builtin_amdgcn_s_barrier();

        // ---- GEMM2 (setprio-wrapped) ----
        f32x4 acc2[4];
#pragma unroll
        for (int mt = 0; mt < 4; ++mt) acc2[mt] = mk4(b2v);
        __builtin_amdgcn_s_setprio(1);
#pragma unroll
        for (int mt = 0; mt < 4; ++mt)
#pragma unroll
            for (int ks = 0; ks < 4; ++ks) {
                bf16x8 ah = *(const bf16x8*)&smem[12288 + (mt * 4 + ks) * 512 + sr * 8];
                acc2[mt] = __builtin_amdgcn_mfma_f32_16x16x32_bf16(ah, wb2[ks], acc2[mt], 0, 0, 0);
            }
        __builtin_amdgcn_s_setprio(0);

        // ---- stores ----
#pragma unroll
        for (int mt = 0; mt < 4; ++mt)
#pragma unroll
            for (int r = 0; r < 4; ++r) {
                long orow = (long)t * 64 + mt * 16 + g * 4 + r;
                if (orow < E) out[orow * 64 + w * 16 + c] = acc2[mt][r];
            }
        // no end barrier: next B1 orders h-WAR, B2 already ordered A-WAR
    }
}

// fallback (ws too small for node table)
__global__ __launch_bounds__(256) void edge_mlp_fallback(
    const float* __restrict__ edge_feats, const float* __restrict__ node_feats,
    const int* __restrict__ senders, const int* __restrict__ receivers,
    const __bf16* __restrict__ W1F, const __bf16* __restrict__ W2F,
    const float* __restrict__ g1, const float* __restrict__ b2,
    float* __restrict__ out, int E, int numTiles)
{
    __shared__ __bf16 A_lds[4 * 6 * 64 * 8];
    __shared__ __bf16 h_frag[4 * 4 * 64 * 8];
    const int lane = threadIdx.x & 63;
    const int w = threadIdx.x >> 6;
    const int c = lane & 15;
    const int g = lane >> 4;
    const int G = gridDim.x;

    bf16x8 wb1[2][6];
#pragma unroll
    for (int nt2 = 0; nt2 < 2; ++nt2)
#pragma unroll
        for (int f = 0; f < 6; ++f)
            wb1[nt2][f] = *(const bf16x8*)(W1F + (((w * 2 + nt2) * 6 + f) * 64 + lane) * 8);
    bf16x8 wb2[4];
#pragma unroll
    for (int ks = 0; ks < 4; ++ks)
        wb2[ks] = *(const bf16x8*)(W2F + ((w * 4 + ks) * 64 + lane) * 8);
    const float g1v0 = g1[w * 32 + c];
    const float g1v1 = g1[w * 32 + 16 + c];
    const float b2v  = b2[w * 16 + c];
    const int sr = SWZ(c * 4 + g);

    for (int t = blockIdx.x; t < numTiles; t += G) {
        long rowc = (long)t * 64 + w * 16 + c;
        if (rowc > (long)E - 1) rowc = (long)E - 1;
        int iR = receivers[rowc], iS = senders[rowc];
        const float* pr = node_feats + ((long)iR << 6) + g * 8;
        const float* ps = node_feats + ((long)iS << 6) + g * 8;
        const float* pe = edge_feats + (rowc << 6) + g * 8;
        f32x4 e0a = *(const f32x4*)(pe),      e0b = *(const f32x4*)(pe + 4);
        f32x4 e1a = *(const f32x4*)(pe + 32), e1b = *(const f32x4*)(pe + 36);
        f32x4 r0a = *(const f32x4*)(pr),      r0b = *(const f32x4*)(pr + 4);
        f32x4 r1a = *(const f32x4*)(pr + 32), r1b = *(const f32x4*)(pr + 36);
        f32x4 s0a = *(const f32x4*)(ps),      s0b = *(const f32x4*)(ps + 4);
        f32x4 s1a = *(const f32x4*)(ps + 32), s1b = *(const f32x4*)(ps + 36);

        __bf16* ab = A_lds + w * 6 * 512 + lane * 8;
        *(bf16x8*)(ab)        = cvt8(e0a, e0b);
        *(bf16x8*)(ab + 512)  = cvt8(e1a, e1b);
        *(bf16x8*)(ab + 1024) = cvt8(r0a, r0b);
        *(bf16x8*)(ab + 1536) = cvt8(r1a, r1b);
        *(bf16x8*)(ab + 2048) = cvt8(s0a, s0b);
        *(bf16x8*)(ab + 2560) = cvt8(s1a, s1b);
        __syncthreads();

        f32x4 acc0[4], acc1[4];
#pragma unroll
        for (int mt = 0; mt < 4; ++mt) { acc0[mt] = mk4(g1v0); acc1[mt] = mk4(g1v1); }
#pragma unroll
        for (int mt = 0; mt < 4; ++mt)
#pragma unroll
            for (int f = 0; f < 6; ++f) {
                bf16x8 a = *(const bf16x8*)(A_lds + ((mt * 6 + f) * 64 + lane) * 8);
                acc0[mt] = __builtin_amdgcn_mfma_f32_16x16x32_bf16(a, wb1[0][f], acc0[mt], 0, 0, 0);
                acc1[mt] = __builtin_amdgcn_mfma_f32_16x16x32_bf16(a, wb1[1][f], acc1[mt], 0, 0, 0);
            }
#pragma unroll
        for (int mt = 0; mt < 4; ++mt)
#pragma unroll
            for (int r = 0; r < 4; ++r) {
                float v0 = acc0[mt][r]; v0 = v0 > 0.f ? v0 : 0.f;
                float v1 = acc1[mt][r]; v1 = v1 > 0.f ? v1 : 0.f;
                bf16x2 pk; pk[0] = (__bf16)v0; pk[1] = (__bf16)v1;
                int s = SWZ(g * 16 + r * 4 + (c >> 2));
                *(bf16x2*)&h_frag[((mt * 4 + w) * 512) + s * 8 + ((c & 3) << 1)] = pk;
            }
        __syncthreads();

        f32x4 acc2[4];
#pragma unroll
        for (int mt = 0; mt < 4; ++mt) acc2[mt] = mk4(b2v);
#pragma unroll
        for (int mt = 0; mt < 4; ++mt)
#pragma unroll
            for (int ks = 0; ks < 4; ++ks) {
                bf16x8 ah = *(const bf16x8*)&h_frag[(mt * 4 + ks) * 512 + sr * 8];
                acc2[mt] = __builtin_amdgcn_mfma_f32_16x16x32_bf16(ah, wb2[ks], acc2[mt], 0, 0, 0);
            }
#pragma unroll
        for (int mt = 0; mt < 4; ++mt)
#pragma unroll
            for (int r = 0; r < 4; ++r) {
                long orow = (long)t * 64 + mt * 16 + g * 4 + r;
                if (orow < E) out[orow * 64 + w * 16 + c] = acc2[mt][r];
            }
        __syncthreads();
    }
}

extern "C" void kernel_launch(void* const* d_in, const int* in_sizes, int n_in,
                              void* d_out, int out_size, void* d_ws, size_t ws_size,
                              hipStream_t stream) {
    const float* edge_feats = (const float*)d_in[0];
    const float* node_feats = (const float*)d_in[1];
    const float* gattr      = (const float*)d_in[2];
    const int*   senders    = (const int*)d_in[3];
    const int*   receivers  = (const int*)d_in[4];
    const float* W1         = (const float*)d_in[5];
    const float* b1         = (const float*)d_in[6];
    const float* W2         = (const float*)d_in[7];
    const float* b2         = (const float*)d_in[8];
    float* out = (float*)d_out;

    const int E = in_sizes[3];        // N_EDGES
    const int N = in_sizes[1] / 64;   // N_NODES

    char* ws = (char*)d_ws;
    __bf16* W1F = (__bf16*)ws;
    __bf16* W2F = (__bf16*)(ws + 49152);
    float*  g1  = (float*)(ws + 49152 + 16384);
    __bf16* nodeBF = (__bf16*)(ws + WS_NODEBF_OFF);

    const size_t ws_needed = (size_t)WS_NODEBF_OFF + (size_t)N * 64 * 2;
    const bool useNB = ws_size >= ws_needed;

    int prep_total = 128 * 192 + 64 * 128 + 128;
    prep_kernel<<<(prep_total + 255) / 256, 256, 0, stream>>>(W1, b1, W2, gattr, W1F, W2F, g1);

    const int numTiles = (E + 63) / 64;
    int grid = numTiles < GRID_MAIN ? numTiles : GRID_MAIN;
    if (useNB) {
        int n8 = N * 8;
        node_conv_kernel<<<(n8 + 255) / 256, 256, 0, stream>>>(node_feats, nodeBF, n8);
        edge_mlp_kernel<<<grid, 256, 0, stream>>>(edge_feats, nodeBF, senders, receivers,
                                                  W1F, W2F, g1, b2, out, E, numTiles);
    } else {
        edge_mlp_fallback<<<grid, 256, 0, stream>>>(edge_feats, node_feats, senders, receivers,
                                                    W1F, W2F, g1, b2, out, E, numTiles);
    }
}